// Round 1
// baseline (3142.772 us; speedup 1.0000x reference)
//
#include <hip/hip_runtime.h>

// 3-layer GCN: per layer  h = x @ W  (N x 64 @ 64 x 64, f32)
//              out[dst] += h[src]    (scatter-add over E edges)
// N = 100000, E = 1200000, D = 64.

#define GCN_D 64

// ---------------- GEMM: H[r, :] = X[r, :] @ W  ----------------
// 256 threads/block, 16 rows/block. W staged in LDS (16 KB), X tile in LDS
// (padded stride 65 to avoid 4-way bank conflict on the broadcast read).
// Thread t: row = t/16, cols = (t%16)*4 .. +3 (float4 accumulate).
__global__ __launch_bounds__(256) void gcn_gemm64(const float* __restrict__ X,
                                                  const float* __restrict__ W,
                                                  float* __restrict__ H,
                                                  int nrows) {
    __shared__ float Wl[64 * 64];
    __shared__ float Xl[16][65];

    const int tid = threadIdx.x;

    // Stage W: 4096 floats = 1024 float4; 4 per thread, coalesced.
    for (int i = tid; i < 1024; i += 256) {
        ((float4*)Wl)[i] = ((const float4*)W)[i];
    }

    const int rowBase = blockIdx.x * 16;
    const int lr = tid >> 4;   // 0..15 local row
    const int lc = tid & 15;   // 0..15 float4-column
    const int grow = rowBase + lr;

    if (grow < nrows) {
        float4 xv = ((const float4*)X)[(long long)grow * 16 + lc];
        Xl[lr][lc * 4 + 0] = xv.x;
        Xl[lr][lc * 4 + 1] = xv.y;
        Xl[lr][lc * 4 + 2] = xv.z;
        Xl[lr][lc * 4 + 3] = xv.w;
    }
    __syncthreads();

    float4 acc = make_float4(0.f, 0.f, 0.f, 0.f);
#pragma unroll
    for (int k = 0; k < 64; ++k) {
        const float xv = Xl[lr][k];                       // 16-lane broadcast
        const float4 w4 = ((const float4*)Wl)[k * 16 + lc]; // b128, conflict-free
        acc.x = fmaf(xv, w4.x, acc.x);
        acc.y = fmaf(xv, w4.y, acc.y);
        acc.z = fmaf(xv, w4.z, acc.z);
        acc.w = fmaf(xv, w4.w, acc.w);
    }

    if (grow < nrows) {
        ((float4*)H)[(long long)grow * 16 + lc] = acc;
    }
}

// ---------------- Scatter-add: out[dst[e], :] += H[src[e], :] ----------------
// 16 lanes per edge; each lane float4-gathers 16 B of the source row and does
// 4 scalar f32 atomicAdds into the destination row.
__global__ __launch_bounds__(256) void gcn_scatter(const float* __restrict__ H,
                                                   const int* __restrict__ ei,
                                                   float* __restrict__ out,
                                                   int nedges) {
    const long long t = (long long)blockIdx.x * 256 + threadIdx.x;
    const int e = (int)(t >> 4);
    if (e >= nedges) return;
    const int lc = (int)(t & 15);

    const int s = ei[e];            // src row
    const int d = ei[nedges + e];   // dst row

    const float4 v = ((const float4*)H)[(long long)s * 16 + lc];
    float* o = out + (long long)d * GCN_D + lc * 4;
    atomicAdd(o + 0, v.x);
    atomicAdd(o + 1, v.y);
    atomicAdd(o + 2, v.z);
    atomicAdd(o + 3, v.w);
}

extern "C" void kernel_launch(void* const* d_in, const int* in_sizes, int n_in,
                              void* d_out, int out_size, void* d_ws, size_t ws_size,
                              hipStream_t stream) {
    const float* x  = (const float*)d_in[0];
    const int*   ei = (const int*)d_in[1];   // [2, E] flat: src then dst
    const float* Ws[3] = {(const float*)d_in[2], (const float*)d_in[3],
                          (const float*)d_in[4]};
    float* out = (float*)d_out;
    float* h   = (float*)d_ws;               // N*64 f32 = 25.6 MB scratch

    const int N_ = in_sizes[0] / GCN_D;
    const int E_ = in_sizes[1] / 2;

    const int gemmBlocks = (N_ + 15) / 16;
    const int scatBlocks = (int)(((long long)E_ * 16 + 255) / 256);

    const float* cur = x;
    for (int l = 0; l < 3; ++l) {
        gcn_gemm64<<<gemmBlocks, 256, 0, stream>>>(cur, Ws[l], h, N_);
        hipMemsetAsync(out, 0, (size_t)N_ * GCN_D * sizeof(float), stream);
        gcn_scatter<<<scatBlocks, 256, 0, stream>>>(h, ei, out, E_);
        cur = out;
    }
}

// Round 2
// 456.886 us; speedup vs baseline: 6.8787x; 6.8787x over previous
//
#include <hip/hip_runtime.h>

// 3-layer GCN on MI355X.
// Per layer (ref): h = x @ W ; out[dst] += h[src].
// We use (S x) W == S (x W): aggregate-by-CSR first (no atomics), then GEMM.
// N = 100000, E = 1200000, D = 64.

#define GCN_D 64

// ---------------- GEMM: OUT[r, :] = X[r, :] @ W ----------------
__global__ __launch_bounds__(256) void gcn_gemm64(const float* __restrict__ X,
                                                  const float* __restrict__ W,
                                                  float* __restrict__ H,
                                                  int nrows) {
    __shared__ float Wl[64 * 64];
    __shared__ float Xl[16][65];

    const int tid = threadIdx.x;
    for (int i = tid; i < 1024; i += 256) {
        ((float4*)Wl)[i] = ((const float4*)W)[i];
    }

    const int rowBase = blockIdx.x * 16;
    const int lr = tid >> 4;
    const int lc = tid & 15;
    const int grow = rowBase + lr;

    if (grow < nrows) {
        float4 xv = ((const float4*)X)[(long long)grow * 16 + lc];
        Xl[lr][lc * 4 + 0] = xv.x;
        Xl[lr][lc * 4 + 1] = xv.y;
        Xl[lr][lc * 4 + 2] = xv.z;
        Xl[lr][lc * 4 + 3] = xv.w;
    }
    __syncthreads();

    float4 acc = make_float4(0.f, 0.f, 0.f, 0.f);
#pragma unroll
    for (int k = 0; k < 64; ++k) {
        const float xv = Xl[lr][k];
        const float4 w4 = ((const float4*)Wl)[k * 16 + lc];
        acc.x = fmaf(xv, w4.x, acc.x);
        acc.y = fmaf(xv, w4.y, acc.y);
        acc.z = fmaf(xv, w4.z, acc.z);
        acc.w = fmaf(xv, w4.w, acc.w);
    }

    if (grow < nrows) {
        ((float4*)H)[(long long)grow * 16 + lc] = acc;
    }
}

// ---------------- CSR build ----------------
__global__ __launch_bounds__(256) void k_hist(const int* __restrict__ ei, int* __restrict__ cnt, int E) {
    int e = blockIdx.x * 256 + threadIdx.x;
    if (e < E) atomicAdd(&cnt[ei[E + e]], 1);   // dst half
}

// Exclusive scan, 1024 elements/block (256 thr x 4).
__global__ __launch_bounds__(256) void k_scan1(const int* __restrict__ in, int* __restrict__ out,
                                               int* __restrict__ bsum, int n) {
    __shared__ int sd[256];
    const int t = threadIdx.x;
    const int base = blockIdx.x * 1024 + t * 4;
    int v[4]; int s = 0;
#pragma unroll
    for (int j = 0; j < 4; ++j) { v[j] = (base + j < n) ? in[base + j] : 0; s += v[j]; }
    sd[t] = s; __syncthreads();
    int x = s;
    for (int off = 1; off < 256; off <<= 1) {
        int y = (t >= off) ? sd[t - off] : 0;
        __syncthreads();
        x += y; sd[t] = x;
        __syncthreads();
    }
    int run = x - s;   // exclusive offset for this thread
#pragma unroll
    for (int j = 0; j < 4; ++j) {
        if (base + j < n) out[base + j] = run;
        run += v[j];
    }
    if (t == 255) bsum[blockIdx.x] = x;   // block total
}

__global__ __launch_bounds__(256) void k_scan2(int* __restrict__ bsum, int nblk) {
    __shared__ int sd[256];
    const int t = threadIdx.x;
    int v = (t < nblk) ? bsum[t] : 0;
    sd[t] = v; __syncthreads();
    int x = v;
    for (int off = 1; off < 256; off <<= 1) {
        int y = (t >= off) ? sd[t - off] : 0;
        __syncthreads();
        x += y; sd[t] = x;
        __syncthreads();
    }
    if (t < nblk) bsum[t] = x - v;   // exclusive
}

__global__ __launch_bounds__(256) void k_scan3(int* __restrict__ rp, const int* __restrict__ bsum,
                                               int* __restrict__ cur, int n, int Nn) {
    const int t = threadIdx.x;
    const int off = bsum[blockIdx.x];
    const int base = blockIdx.x * 1024 + t * 4;
#pragma unroll
    for (int j = 0; j < 4; ++j) {
        int i = base + j;
        if (i < n) {
            int v = rp[i] + off;
            rp[i] = v;
            if (i < Nn) cur[i] = v;
        }
    }
}

__global__ __launch_bounds__(256) void k_fill(const int* __restrict__ ei, int* __restrict__ cur,
                                              int* __restrict__ cs, int E) {
    int e = blockIdx.x * 256 + threadIdx.x;
    if (e < E) {
        int d = ei[E + e];
        int p = atomicAdd(&cur[d], 1);
        cs[p] = ei[e];   // src
    }
}

// ---------------- Aggregation: out[r,:] = sum_{e in row r} X[cs[e],:] ----------------
// One wave per dst row; lane d owns feature d. Coalesced 256 B gathers, no atomics.
__global__ __launch_bounds__(256) void k_agg(const float* __restrict__ X,
                                             const int* __restrict__ rp,
                                             const int* __restrict__ cs,
                                             float* __restrict__ out, int N) {
    const int w = (int)((blockIdx.x * 256 + threadIdx.x) >> 6);
    if (w >= N) return;
    const int lane = threadIdx.x & 63;
    const int e0 = __builtin_amdgcn_readfirstlane(rp[w]);
    const int e1 = __builtin_amdgcn_readfirstlane(rp[w + 1]);
    float acc = 0.f;
    for (int e = e0; e < e1; ++e) {
        const int s = cs[e];                       // wave-uniform (scalar) load
        acc += X[(long long)s * GCN_D + lane];     // 256 B coalesced gather
    }
    out[(long long)w * GCN_D + lane] = acc;
}

// ---------------- Fallback (R1 path): atomic scatter ----------------
__global__ __launch_bounds__(256) void gcn_scatter(const float* __restrict__ H,
                                                   const int* __restrict__ ei,
                                                   float* __restrict__ out,
                                                   int nedges) {
    const long long t = (long long)blockIdx.x * 256 + threadIdx.x;
    const int e = (int)(t >> 4);
    if (e >= nedges) return;
    const int lc = (int)(t & 15);
    const int s = ei[e];
    const int d = ei[nedges + e];
    const float4 v = ((const float4*)H)[(long long)s * 16 + lc];
    float* o = out + (long long)d * GCN_D + lc * 4;
    atomicAdd(o + 0, v.x);
    atomicAdd(o + 1, v.y);
    atomicAdd(o + 2, v.z);
    atomicAdd(o + 3, v.w);
}

extern "C" void kernel_launch(void* const* d_in, const int* in_sizes, int n_in,
                              void* d_out, int out_size, void* d_ws, size_t ws_size,
                              hipStream_t stream) {
    const float* x  = (const float*)d_in[0];
    const int*   ei = (const int*)d_in[1];   // [2, E] flat: src then dst (int32)
    const float* Ws[3] = {(const float*)d_in[2], (const float*)d_in[3],
                          (const float*)d_in[4]};
    float* out = (float*)d_out;

    const int N_ = in_sizes[0] / GCN_D;
    const int E_ = in_sizes[1] / 2;
    const int n  = N_ + 1;                    // scan length
    const int nblk = (n + 1023) / 1024;

    // ws layout: h | rp | cnt | cur | bsum | cs
    float* h   = (float*)d_ws;
    int*   rp  = (int*)(h + (size_t)N_ * GCN_D);
    int*   cnt = rp + n;
    int*   cur = cnt + n;
    int*   bsum = cur + N_;
    int*   cs  = bsum + 256;
    const size_t needed = (size_t)N_ * GCN_D * 4 + 4ull * (n + n + N_ + 256 + E_);

    const int gemmBlocks = (N_ + 15) / 16;
    const int edgeBlocks = (E_ + 255) / 256;
    const int aggBlocks  = (N_ + 3) / 4;      // 4 waves/block, 1 wave/row

    if (ws_size >= needed) {
        // ---- CSR build (once; reused for all 3 layers) ----
        hipMemsetAsync(cnt, 0, (size_t)n * 4, stream);
        k_hist <<<edgeBlocks, 256, 0, stream>>>(ei, cnt, E_);
        k_scan1<<<nblk, 256, 0, stream>>>(cnt, rp, bsum, n);
        k_scan2<<<1, 256, 0, stream>>>(bsum, nblk);
        k_scan3<<<nblk, 256, 0, stream>>>(rp, bsum, cur, n, N_);
        k_fill <<<edgeBlocks, 256, 0, stream>>>(ei, cur, cs, E_);

        // ---- 3 layers: agg (S·x) then GEMM (·W) ----
        const float* curAct = x;
        for (int l = 0; l < 3; ++l) {
            k_agg<<<aggBlocks, 256, 0, stream>>>(curAct, rp, cs, h, N_);
            gcn_gemm64<<<gemmBlocks, 256, 0, stream>>>(h, Ws[l], out, N_);
            curAct = out;
        }
    } else {
        // Fallback: R1 atomic path (needs only h).
        const int scatBlocks = (int)(((long long)E_ * 16 + 255) / 256);
        const float* curAct = x;
        for (int l = 0; l < 3; ++l) {
            gcn_gemm64<<<gemmBlocks, 256, 0, stream>>>(curAct, Ws[l], h, N_);
            hipMemsetAsync(out, 0, (size_t)N_ * GCN_D * sizeof(float), stream);
            gcn_scatter<<<scatBlocks, 256, 0, stream>>>(h, ei, out, E_);
            curAct = out;
        }
    }
}